// Round 5
// baseline (3890.833 us; speedup 1.0000x reference)
//
#include <hip/hip_runtime.h>
#include <math.h>

#define Bq 4
#define Sq 4096
#define Dq 1024
#define Hq 128
#define Mq 256
#define Rq 64
#define Cq 64
#define NCHUNK 64
#define BSq (Bq*Sq)

typedef __attribute__((ext_vector_type(8))) short short8;
typedef __attribute__((ext_vector_type(4))) float f32x4;

__device__ __forceinline__ float softplusf_(float x){
  return fmaxf(x,0.f) + log1pf(expf(-fabsf(x)));
}
__device__ __forceinline__ float sigmoidf_(float x){
  return 1.f/(1.f+__expf(-x));
}
__device__ __forceinline__ unsigned short bf16rn(float x){
  unsigned u = __float_as_uint(x);
  u += 0x7fffu + ((u>>16)&1u);
  return (unsigned short)(u>>16);
}
__device__ __forceinline__ float bf16tof(unsigned short s){
  return __uint_as_float(((unsigned)s)<<16);
}
// branchless erf-gelu (A&S 7.1.26, |err|<=1.5e-7)
__device__ __forceinline__ float gelu_fast(float x){
  float z  = x*0.70710678118f;
  float az = fabsf(z);
  float t  = __builtin_amdgcn_rcpf(fmaf(0.3275911f, az, 1.f));
  float p  = fmaf(t, 1.061405429f, -1.453152027f);
  p = fmaf(t, p, 1.421413741f);
  p = fmaf(t, p, -0.284496736f);
  p = fmaf(t, p, 0.254829592f);
  p = p*t;
  float e  = __expf(-az*az);
  float er = copysignf(1.f - p*e, z);
  return 0.5f*x*(1.f + er);
}

// ---------------- bf16x3 MFMA GEMM (256 thr) ----------------
template<int BN, int ACT>
__global__ __launch_bounds__(256) void gemm_bf3(
    const float* __restrict__ Af,
    const unsigned short* __restrict__ BhT, const unsigned short* __restrict__ BlT,
    float* __restrict__ C, const float* __restrict__ gate, int N, int K)
{
  constexpr int BM = 128;
  constexpr int PK = 40;
  constexpr int TN = BN/32;
  __shared__ __align__(16) unsigned short As[2][BM*PK];
  __shared__ __align__(16) unsigned short Bs[2][BN*PK];
  const int tid = threadIdx.x;
  const int bm = blockIdx.y*BM, bn = blockIdx.x*BN;
  const int wv = tid>>6, lane = tid&63;
  const int n16 = lane&15, q = lane>>4;
  const int wm = wv>>1, wn = wv&1;

  f32x4 acc[4][TN];
  #pragma unroll
  for (int i=0;i<4;i++){
    #pragma unroll
    for (int j=0;j<TN;j++){ f32x4 z={0.f,0.f,0.f,0.f}; acc[i][j]=z; }
  }
  for (int k0=0;k0<K;k0+=32){
    #pragma unroll
    for (int c0=0;c0<BM*8;c0+=256){
      int c = c0 + tid;
      int row = c>>3, kg = (c&7)*4;
      float4 v = *(const float4*)&Af[(size_t)(bm+row)*K + k0+kg];
      unsigned short h0=bf16rn(v.x),h1=bf16rn(v.y),h2=bf16rn(v.z),h3=bf16rn(v.w);
      unsigned short l0=bf16rn(v.x-bf16tof(h0)),l1=bf16rn(v.y-bf16tof(h1));
      unsigned short l2=bf16rn(v.z-bf16tof(h2)),l3=bf16rn(v.w-bf16tof(h3));
      int off = row*PK+kg;
      *(unsigned*)&As[0][off]   = (unsigned)h0 | ((unsigned)h1<<16);
      *(unsigned*)&As[0][off+2] = (unsigned)h2 | ((unsigned)h3<<16);
      *(unsigned*)&As[1][off]   = (unsigned)l0 | ((unsigned)l1<<16);
      *(unsigned*)&As[1][off+2] = (unsigned)l2 | ((unsigned)l3<<16);
    }
    #pragma unroll
    for (int c0=0;c0<BN*4;c0+=256){
      int c = c0 + tid;
      int row = c>>2, kg = (c&3)*8;
      *(short8*)&Bs[0][row*PK+kg] = *(const short8*)&BhT[(size_t)(bn+row)*K + k0+kg];
      *(short8*)&Bs[1][row*PK+kg] = *(const short8*)&BlT[(size_t)(bn+row)*K + k0+kg];
    }
    __syncthreads();
    short8 a_h[4], a_l[4], b_h[TN], b_l[TN];
    #pragma unroll
    for (int i=0;i<4;i++){
      int r = wm*64 + i*16 + n16;
      a_h[i] = *(const short8*)&As[0][r*PK + q*8];
      a_l[i] = *(const short8*)&As[1][r*PK + q*8];
    }
    #pragma unroll
    for (int j=0;j<TN;j++){
      int r = wn*(BN/2) + j*16 + n16;
      b_h[j] = *(const short8*)&Bs[0][r*PK + q*8];
      b_l[j] = *(const short8*)&Bs[1][r*PK + q*8];
    }
    #pragma unroll
    for (int i=0;i<4;i++){
      #pragma unroll
      for (int j=0;j<TN;j++){
        acc[i][j] = __builtin_amdgcn_mfma_f32_16x16x32_bf16(a_h[i], b_h[j], acc[i][j], 0,0,0);
        acc[i][j] = __builtin_amdgcn_mfma_f32_16x16x32_bf16(a_l[i], b_h[j], acc[i][j], 0,0,0);
        acc[i][j] = __builtin_amdgcn_mfma_f32_16x16x32_bf16(a_h[i], b_l[j], acc[i][j], 0,0,0);
      }
    }
    __syncthreads();
  }
  #pragma unroll
  for (int i=0;i<4;i++){
    #pragma unroll
    for (int j=0;j<TN;j++){
      #pragma unroll
      for (int r=0;r<4;r++){
        int row = bm + wm*64 + i*16 + q*4 + r;
        int col = bn + wn*(BN/2) + j*16 + n16;
        float v = acc[i][j][r];
        if (ACT==1) v = softplusf_(v);
        else if (ACT==2) v = sigmoidf_(v);
        else if (ACT==3) v *= sigmoidf_(gate[(size_t)row*N+col]);
        C[(size_t)row*N+col] = v;
      }
    }
  }
}

__global__ void splitT(const float* __restrict__ W,
                       unsigned short* __restrict__ hT, unsigned short* __restrict__ lT,
                       int K, int N)
{
  int idx = blockIdx.x*256 + threadIdx.x;
  if (idx >= N*K) return;
  int nn = idx / K, k = idx - nn*K;
  float v = W[(size_t)k*N + nn];
  unsigned short h = bf16rn(v);
  hT[idx] = h;
  lT[idx] = bf16rn(v - bf16tof(h));
}

__global__ __launch_bounds__(128) void conv_ln_kernel(
  const float* __restrict__ k_raw, const float* __restrict__ v_raw,
  const float* __restrict__ conv_w, const float* __restrict__ conv_b,
  const float* __restrict__ kn_g, const float* __restrict__ kn_b,
  float* __restrict__ k_out, float* __restrict__ v_out)
{
  int s = blockIdx.x, b = blockIdx.y, which = blockIdx.z;
  int h = threadIdx.x;
  const float* src = (which==0) ? k_raw : v_raw;
  float acc = conv_b[h];
  #pragma unroll
  for (int j=0;j<4;j++){
    int ss = s-3+j;
    if (ss>=0) acc += conv_w[h*4+j]*src[((size_t)b*Sq+ss)*Hq + h];
  }
  if (which==0){
    __shared__ float red[4];
    float sv = acc, s2 = acc*acc;
    #pragma unroll
    for (int off=32; off>0; off>>=1){
      sv += __shfl_down(sv, off, 64);
      s2 += __shfl_down(s2, off, 64);
    }
    if ((h&63)==0){ red[(h>>6)*2]=sv; red[(h>>6)*2+1]=s2; }
    __syncthreads();
    float mean = (red[0]+red[2])*(1.f/128.f);
    float var  = (red[1]+red[3])*(1.f/128.f) - mean*mean;
    float y = (acc-mean)*rsqrtf(var+1e-5f)*kn_g[h]+kn_b[h];
    k_out[((size_t)b*Sq+s)*Hq + h] = y;
  } else {
    v_out[((size_t)b*Sq+s)*Hq + h] = acc;
  }
}

// ---- scan-branch LDS offsets (bytes) ----
#define OFF_KCH   0            // 64*128*2 = 16384
#define OFF_KCL   16384
#define OFF_ACTH  32768        // 64*256*2 = 32768
#define OFF_SAM   65536        // 256*4
#define OFF_PUS   66560        // 2*128*4
#define OFF_SEN   67584        // 64*4
#define OFF_PEN   67840        // 8*64*4
#define OFF_SAB   69888        // 128*4
#define OFF_SEB   70400        // 128*4
#define OFF_SABP  70912        // 2*4
#define OFF_SEBP  70920        // 2*4
#define LDS_TOTAL 70928        // Wg branch needs 40960 < this

// Fused: blocks 0..3 = scan (1/batch, 16 waves); blocks 4.. = Wg GEMM tiles.
__global__ __launch_bounds__(1024) void fused_scan_wg(
  const float* __restrict__ k_ln, const float* __restrict__ v_c,
  const float* __restrict__ eta, const float* __restrict__ delta,
  const float* __restrict__ alpha,
  const float* __restrict__ mW1, const float* __restrict__ mb1,
  const float* __restrict__ mW2, const float* __restrict__ mb2,
  float* __restrict__ combined,
  const float* __restrict__ x,
  const unsigned short* __restrict__ WgTh, const unsigned short* __restrict__ WgTl,
  float* __restrict__ glog)
{
  __shared__ __align__(16) char smem[LDS_TOTAL];
  const int blk = blockIdx.x;
  const int tid = threadIdx.x;
  const int wv = tid >> 6;
  const int lane = tid & 63;
  const int n = lane & 15;
  const int q = lane >> 4;

  if (blk >= 4){
    // ===== Wg GEMM branch: 128x128 tile, 16 waves of 32x32 =====
    unsigned short* As_h = (unsigned short*)smem;   // 128*40
    unsigned short* As_l = As_h + 5120;
    unsigned short* Bs_h = As_l + 5120;
    unsigned short* Bs_l = Bs_h + 5120;
    const int g = blk - 4;
    const int bm = (g>>3)*128, bn = (g&7)*128;
    const int wm = wv&3, wn = wv>>2;
    f32x4 acc[2][2];
    #pragma unroll
    for (int i=0;i<2;i++){
      #pragma unroll
      for (int j=0;j<2;j++){ f32x4 z={0.f,0.f,0.f,0.f}; acc[i][j]=z; }
    }
    for (int k0=0;k0<Dq;k0+=32){
      {
        int row = tid>>3, kg = (tid&7)*4;
        float4 v = *(const float4*)&x[(size_t)(bm+row)*Dq + k0+kg];
        unsigned short h0=bf16rn(v.x),h1=bf16rn(v.y),h2=bf16rn(v.z),h3=bf16rn(v.w);
        unsigned short l0=bf16rn(v.x-bf16tof(h0)),l1=bf16rn(v.y-bf16tof(h1));
        unsigned short l2=bf16rn(v.z-bf16tof(h2)),l3=bf16rn(v.w-bf16tof(h3));
        int off = row*40+kg;
        *(unsigned*)&As_h[off]   = (unsigned)h0 | ((unsigned)h1<<16);
        *(unsigned*)&As_h[off+2] = (unsigned)h2 | ((unsigned)h3<<16);
        *(unsigned*)&As_l[off]   = (unsigned)l0 | ((unsigned)l1<<16);
        *(unsigned*)&As_l[off+2] = (unsigned)l2 | ((unsigned)l3<<16);
      }
      if (tid < 512){
        int row = tid>>2, kg = (tid&3)*8;
        *(short8*)&Bs_h[row*40+kg] = *(const short8*)&WgTh[(size_t)(bn+row)*Dq + k0+kg];
        *(short8*)&Bs_l[row*40+kg] = *(const short8*)&WgTl[(size_t)(bn+row)*Dq + k0+kg];
      }
      __syncthreads();
      short8 a_h[2], a_l[2], b_h[2], b_l[2];
      #pragma unroll
      for (int i=0;i<2;i++){
        int r = wm*32 + i*16 + n;
        a_h[i] = *(const short8*)&As_h[r*40 + q*8];
        a_l[i] = *(const short8*)&As_l[r*40 + q*8];
      }
      #pragma unroll
      for (int j=0;j<2;j++){
        int r = wn*32 + j*16 + n;
        b_h[j] = *(const short8*)&Bs_h[r*40 + q*8];
        b_l[j] = *(const short8*)&Bs_l[r*40 + q*8];
      }
      #pragma unroll
      for (int i=0;i<2;i++){
        #pragma unroll
        for (int j=0;j<2;j++){
          acc[i][j] = __builtin_amdgcn_mfma_f32_16x16x32_bf16(a_h[i], b_h[j], acc[i][j], 0,0,0);
          acc[i][j] = __builtin_amdgcn_mfma_f32_16x16x32_bf16(a_l[i], b_h[j], acc[i][j], 0,0,0);
          acc[i][j] = __builtin_amdgcn_mfma_f32_16x16x32_bf16(a_h[i], b_l[j], acc[i][j], 0,0,0);
        }
      }
      __syncthreads();
    }
    #pragma unroll
    for (int i=0;i<2;i++){
      #pragma unroll
      for (int j=0;j<2;j++){
        #pragma unroll
        for (int r=0;r<4;r++){
          int row = bm + wm*32 + i*16 + q*4 + r;
          int col = bn + wn*32 + j*16 + n;
          glog[(size_t)row*Dq+col] = acc[i][j][r];
        }
      }
    }
    return;
  }

  // ===== scan branch: 16 waves =====
  unsigned short* kc_hi  = (unsigned short*)(smem + OFF_KCH);
  unsigned short* kc_lo  = (unsigned short*)(smem + OFF_KCL);
  unsigned short* act_hi = (unsigned short*)(smem + OFF_ACTH);
  float* Sam = (float*)(smem + OFF_SAM);
  float* pus = (float*)(smem + OFF_PUS);   // [2][128]
  float* Sen = (float*)(smem + OFF_SEN);
  float* pen = (float*)(smem + OFF_PEN);   // [8][64]
  float* Sab = (float*)(smem + OFF_SAB);
  float* Seb = (float*)(smem + OFF_SEB);
  float* Sabp = (float*)(smem + OFF_SABP);
  float* Sebp = (float*)(smem + OFF_SEBP);

  const int b = blk;
  const int m_own = wv*16 + n;          // GEMM1 m-tile = wv
  const int ht = wv>>1;                 // GEMM2 h-tile
  const int co = (wv&1)*2;              // GEMM2 first c-tile
  const int h2 = ht*16 + n;

  float w1m[4][8];      // W1[m_own][h=ks*32+q*8+j]
  float w2m[8][8];      // W2[h2][m=ks2*32+q*8+j]
  unsigned w2tp[4][4];  // bf16-packed W2[h=ks*32+q*8+{2jj,2jj+1}][m_own]
  float b1reg, b2reg;
  #pragma unroll
  for (int ks=0;ks<4;ks++){
    const float* p = mW1 + (size_t)m_own*Hq + ks*32 + q*8;
    #pragma unroll
    for (int j=0;j<8;j++) w1m[ks][j] = p[j];
    #pragma unroll
    for (int jj=0;jj<4;jj++){
      float x0 = mW2[(size_t)(ks*32+q*8+2*jj)*Mq + m_own];
      float x1 = mW2[(size_t)(ks*32+q*8+2*jj+1)*Mq + m_own];
      w2tp[ks][jj] = (unsigned)bf16rn(x0) | ((unsigned)bf16rn(x1)<<16);
    }
  }
  #pragma unroll
  for (int ks2=0;ks2<8;ks2++){
    const float* p = mW2 + (size_t)h2*Mq + ks2*32 + q*8;
    #pragma unroll
    for (int j=0;j<8;j++) w2m[ks2][j] = p[j];
  }
  b1reg = mb1[m_own];
  b2reg = mb2[h2];

  // prefetch chunk 0
  float4 kcp[2]; float abv=0.f, ebv=0.f;
  {
    const float* kcg = k_ln + (size_t)b*Sq*Hq;
    #pragma unroll
    for (int r=0;r<2;r++) kcp[r] = *(const float4*)(kcg + (size_t)(tid+1024*r)*4);
    if (tid < 128){
      abv = alpha[(size_t)b*Sq*Hq + 63*Hq + tid];
      ebv = eta[(size_t)b*Sq*Hq + 63*Hq + tid];
    }
  }

  for (int t=0; t<NCHUNK; ++t){
    __syncthreads();   // B1: guard LDS reuse vs prev updates
    const size_t base = ((size_t)b*Sq + (size_t)t*Cq)*Hq;
    const float ab_c = abv, eb_c = ebv;
    // ---- P0: kc regs -> LDS bf16 hi/lo (swizzled); Sab/Seb; aw/ew partials ----
    #pragma unroll
    for (int r=0;r<2;r++){
      int i4 = tid + 1024*r;
      int c = i4>>5, h0 = (i4&31)<<2;
      float4 v = kcp[r];
      int pg  = (h0>>3) ^ (c & 15);
      int off = c*Hq + (pg<<3) + (h0&7);
      unsigned short h0s=bf16rn(v.x), h1s=bf16rn(v.y), h2s=bf16rn(v.z), h3s=bf16rn(v.w);
      unsigned short l0s=bf16rn(v.x-bf16tof(h0s)), l1s=bf16rn(v.y-bf16tof(h1s));
      unsigned short l2s=bf16rn(v.z-bf16tof(h2s)), l3s=bf16rn(v.w-bf16tof(h3s));
      *(unsigned*)&kc_hi[off]   = (unsigned)h0s | ((unsigned)h1s<<16);
      *(unsigned*)&kc_hi[off+2] = (unsigned)h2s | ((unsigned)h3s<<16);
      *(unsigned*)&kc_lo[off]   = (unsigned)l0s | ((unsigned)l1s<<16);
      *(unsigned*)&kc_lo[off+2] = (unsigned)l2s | ((unsigned)l3s<<16);
    }
    if (tid < 128){ Sab[tid] = ab_c; Seb[tid] = eb_c; }
    if (wv < 2){
      float a2 = ab_c, e2 = eb_c;
      #pragma unroll
      for (int mk=1;mk<64;mk<<=1){ a2 += __shfl_xor(a2,mk,64); e2 += __shfl_xor(e2,mk,64); }
      if (lane==0){ Sabp[wv] = a2; Sebp[wv] = e2; }
    }
    // prefetch next chunk (drains under GEMM1)
    {
      int tn = (t+1 < NCHUNK) ? t+1 : t;
      const float* kcg = k_ln + ((size_t)b*Sq + (size_t)tn*Cq)*Hq;
      #pragma unroll
      for (int r=0;r<2;r++) kcp[r] = *(const float4*)(kcg + (size_t)(tid+1024*r)*4);
      if (tid < 128){
        size_t last = ((size_t)b*Sq + (size_t)tn*Cq + 63)*Hq + tid;
        abv = alpha[last]; ebv = eta[last];
      }
    }
    __syncthreads();   // B2

    // ---- GEMM1: inter[:, m-tile wv] = kc @ W1^T (3-MFMA hi/lo) ----
    f32x4 acc1[4];
    #pragma unroll
    for (int ct=0;ct<4;ct++){ f32x4 z={0.f,0.f,0.f,0.f}; acc1[ct]=z; }
    #pragma unroll
    for (int ks=0;ks<4;ks++){
      short8 bh, bl;
      #pragma unroll
      for (int j=0;j<8;j++){
        float xv = w1m[ks][j];
        unsigned short hs = bf16rn(xv);
        bh[j] = (short)hs;
        bl[j] = (short)bf16rn(xv - bf16tof(hs));
      }
      #pragma unroll
      for (int ct=0;ct<4;ct++){
        int off = (ct*16+n)*Hq + ((((ks*4+q)^n))<<3);
        short8 ah = *(const short8*)&kc_hi[off];
        short8 al = *(const short8*)&kc_lo[off];
        acc1[ct] = __builtin_amdgcn_mfma_f32_16x16x32_bf16(ah, bh, acc1[ct], 0,0,0);
        acc1[ct] = __builtin_amdgcn_mfma_f32_16x16x32_bf16(al, bh, acc1[ct], 0,0,0);
        acc1[ct] = __builtin_amdgcn_mfma_f32_16x16x32_bf16(ah, bl, acc1[ct], 0,0,0);
      }
    }
    // gelu -> act_hi + am
    {
      float amsum = 0.f;
      #pragma unroll
      for (int ct=0;ct<4;ct++){
        #pragma unroll
        for (int r=0;r<4;r++){
          float g = gelu_fast(acc1[ct][r] + b1reg);
          amsum += g;
          int c = ct*16 + q*4 + r;
          int pg = (m_own>>3) ^ (c & 15);
          act_hi[c*Mq + (pg<<3) + (m_own&7)] = bf16rn(g);
        }
      }
      amsum += __shfl_xor(amsum, 16, 64);
      amsum += __shfl_xor(amsum, 32, 64);
      if (q==0) Sam[m_own] = amsum*(1.f/64.f);
    }
    __syncthreads();   // B3

    // ---- GEMM2 (2 c-tiles per wave): out = act @ W2^T (act hi, W2 hi/lo) ----
    float vp[8], dp[8];
    #pragma unroll
    for (int i=0;i<2;i++){
      #pragma unroll
      for (int r=0;r<4;r++){
        int c = (co+i)*16 + q*4 + r;
        vp[i*4+r] = v_c[base + (size_t)c*Hq + h2];
        dp[i*4+r] = delta[base + (size_t)c*Hq + h2];
      }
    }
    f32x4 acc2[2];
    #pragma unroll
    for (int i=0;i<2;i++){ f32x4 z={0.f,0.f,0.f,0.f}; acc2[i]=z; }
    #pragma unroll
    for (int ks2=0;ks2<8;ks2++){
      short8 bh, bl;
      #pragma unroll
      for (int j=0;j<8;j++){
        float xv = w2m[ks2][j];
        unsigned short hs = bf16rn(xv);
        bh[j] = (short)hs;
        bl[j] = (short)bf16rn(xv - bf16tof(hs));
      }
      #pragma unroll
      for (int i=0;i<2;i++){
        int off = ((co+i)*16+n)*Mq + ((((ks2*4+q)^n))<<3);
        short8 ah = *(const short8*)&act_hi[off];
        acc2[i] = __builtin_amdgcn_mfma_f32_16x16x32_bf16(ah, bh, acc2[i], 0,0,0);
        acc2[i] = __builtin_amdgcn_mfma_f32_16x16x32_bf16(ah, bl, acc2[i], 0,0,0);
      }
    }
    float err[8];
    {
      float* cb = combined + base;
      #pragma unroll
      for (int i=0;i<2;i++){
        #pragma unroll
        for (int r=0;r<4;r++){
          int c = (co+i)*16 + q*4 + r;
          float o = acc2[i][r] + b2reg;
          cb[(size_t)c*Hq + h2] = o;
          err[i*4+r] = o - vp[i*4+r];
        }
      }
      #pragma unroll
      for (int i=0;i<2;i++){
        #pragma unroll
        for (int r=0;r<4;r++){
          float s = err[i*4+r]*err[i*4+r];
          s += __shfl_xor(s,1,64); s += __shfl_xor(s,2,64);
          s += __shfl_xor(s,4,64); s += __shfl_xor(s,8,64);
          if (n==0) pen[ht*64 + (co+i)*16 + q*4 + r] = s;
        }
      }
    }
    __syncthreads();   // B4
    if (tid < Cq){
      float s = 0.f;
      #pragma unroll
      for (int k=0;k<8;k++) s += pen[k*64 + tid];
      Sen[tid] = sqrtf(s);
    }
    __syncthreads();   // B5
    // grad (only its c-mean is needed downstream)
    {
      float uss = 0.f;
      #pragma unroll
      for (int i=0;i<2;i++){
        #pragma unroll
        for (int r=0;r<4;r++){
          int c = (co+i)*16 + q*4 + r;
          float en = Sen[c];
          float dv = dp[i*4+r];
          float e = err[i*4+r];
          uss += (en > dv) ? dv*e*__builtin_amdgcn_rcpf(en+1e-9f) : e;
        }
      }
      uss += __shfl_xor(uss,16,64);
      uss += __shfl_xor(uss,32,64);
      if (q==0) pus[(wv&1)*128 + h2] = uss;
    }
    __syncthreads();   // B6
    // ---- state updates (registers) ----
    {
      float aw = (Sabp[0]+Sabp[1])*(1.f/128.f);
      float ew = (Sebp[0]+Sebp[1])*(1.f/128.f);
      float amm = Sam[m_own];
      float part = 0.f;
      #pragma unroll
      for (int ks=0;ks<4;ks++){
        float4 u0 = *(const float4*)&pus[ks*32 + q*8];
        float4 u1 = *(const float4*)&pus[ks*32 + q*8 + 4];
        float4 v0 = *(const float4*)&pus[128 + ks*32 + q*8];
        float4 v1 = *(const float4*)&pus[128 + ks*32 + q*8 + 4];
        float us8[8];
        #pragma unroll
        for (int j=0;j<4;j++){
          us8[j]   = (u0[j]+v0[j])*(1.f/64.f);
          us8[j+4] = (u1[j]+v1[j])*(1.f/64.f);
        }
        #pragma unroll
        for (int j=0;j<8;j++)
          w1m[ks][j] = aw*w1m[ks][j] - ew*amm*us8[j];
        #pragma unroll
        for (int jj=0;jj<4;jj++){
          float wa = bf16tof((unsigned short)(w2tp[ks][jj]&0xffffu));
          float wb = bf16tof((unsigned short)(w2tp[ks][jj]>>16));
          float ua = us8[2*jj], ub = us8[2*jj+1];
          wa = aw*wa - ew*ua*amm;
          wb = aw*wb - ew*ub*amm;
          part += ua*wa + ub*wb;
          w2tp[ks][jj] = (unsigned)bf16rn(wa) | ((unsigned)bf16rn(wb)<<16);
        }
      }
      part += __shfl_xor(part, 16, 64);
      part += __shfl_xor(part, 32, 64);
      b1reg = aw*b1reg - ew*part;     // b1u = us . nW2[:,m_own]
      float ush2 = (pus[h2]+pus[128+h2])*(1.f/64.f);
      float eus = ew*ush2;
      #pragma unroll
      for (int ks2=0;ks2<8;ks2++){
        float4 a0 = *(const float4*)&Sam[ks2*32 + q*8];
        float4 a1 = *(const float4*)&Sam[ks2*32 + q*8 + 4];
        #pragma unroll
        for (int j=0;j<4;j++){
          w2m[ks2][j]   = aw*w2m[ks2][j]   - eus*a0[j];
          w2m[ks2][j+4] = aw*w2m[ks2][j+4] - eus*a1[j];
        }
      }
      b2reg = Sab[h2]*b2reg - Seb[h2]*ush2;
    }
  }
}

extern "C" void kernel_launch(void* const* d_in, const int* in_sizes, int n_in,
                              void* d_out, int out_size, void* d_ws, size_t ws_size,
                              hipStream_t stream)
{
  const float* x    = (const float*)d_in[0];
  // d_in[1]=Wq, d_in[14],[15]=qn_g/qn_b: dead (q path unused by output).
  const float* Wk   = (const float*)d_in[2];
  const float* Wv   = (const float*)d_in[3];
  const float* Wo   = (const float*)d_in[4];
  const float* Wg   = (const float*)d_in[5];
  const float* We1  = (const float*)d_in[6];
  const float* We2  = (const float*)d_in[7];
  const float* Wd1  = (const float*)d_in[8];
  const float* Wd2  = (const float*)d_in[9];
  const float* Wa1  = (const float*)d_in[10];
  const float* Wa2  = (const float*)d_in[11];
  const float* conv_w = (const float*)d_in[12];
  const float* conv_b = (const float*)d_in[13];
  const float* kn_g = (const float*)d_in[16];
  const float* kn_b = (const float*)d_in[17];
  const float* mW1  = (const float*)d_in[18];
  const float* mb1  = (const float*)d_in[19];
  const float* mW2  = (const float*)d_in[20];
  const float* mb2  = (const float*)d_in[21];
  float* out = (float*)d_out;

  float* ws = (float*)d_ws;
  size_t o = 0;
  float* k_raw = ws + o; o += (size_t)BSq*Hq;
  float* v_raw = ws + o; o += (size_t)BSq*Hq;
  float* te    = ws + o; o += (size_t)BSq*Rq;
  float* td    = ws + o; o += (size_t)BSq*Rq;
  float* ta    = ws + o; o += (size_t)BSq*Rq;
  float* glog  = ws + o; o += (size_t)BSq*Dq;
  float* etab  = ws + o; o += (size_t)BSq*Hq;
  float* deltab= ws + o; o += (size_t)BSq*Hq;
  float* alphab= ws + o; o += (size_t)BSq*Hq;
  float* k_ln  = ws + o; o += (size_t)BSq*Hq;
  float* v_c   = ws + o; o += (size_t)BSq*Hq;
  float* comb  = ws + o; o += (size_t)BSq*Hq;
  unsigned short* us = (unsigned short*)(ws + o);
  size_t u = 0;
  unsigned short *WkTh = us+u; u += (size_t)Hq*Dq;  unsigned short *WkTl = us+u; u += (size_t)Hq*Dq;
  unsigned short *WvTh = us+u; u += (size_t)Hq*Dq;  unsigned short *WvTl = us+u; u += (size_t)Hq*Dq;
  unsigned short *We1Th= us+u; u += (size_t)Rq*Dq;  unsigned short *We1Tl= us+u; u += (size_t)Rq*Dq;
  unsigned short *Wd1Th= us+u; u += (size_t)Rq*Dq;  unsigned short *Wd1Tl= us+u; u += (size_t)Rq*Dq;
  unsigned short *Wa1Th= us+u; u += (size_t)Rq*Dq;  unsigned short *Wa1Tl= us+u; u += (size_t)Rq*Dq;
  unsigned short *WgTh = us+u; u += (size_t)Dq*Dq;  unsigned short *WgTl = us+u; u += (size_t)Dq*Dq;
  unsigned short *We2Th= us+u; u += (size_t)Hq*Rq;  unsigned short *We2Tl= us+u; u += (size_t)Hq*Rq;
  unsigned short *Wd2Th= us+u; u += (size_t)Hq*Rq;  unsigned short *Wd2Tl= us+u; u += (size_t)Hq*Rq;
  unsigned short *Wa2Th= us+u; u += (size_t)Hq*Rq;  unsigned short *Wa2Tl= us+u; u += (size_t)Hq*Rq;
  unsigned short *WoTh = us+u; u += (size_t)Dq*Hq;  unsigned short *WoTl = us+u; u += (size_t)Dq*Hq;

  splitT<<<(Hq*Dq+255)/256, 256, 0, stream>>>(Wk,  WkTh,  WkTl,  Dq, Hq);
  splitT<<<(Hq*Dq+255)/256, 256, 0, stream>>>(Wv,  WvTh,  WvTl,  Dq, Hq);
  splitT<<<(Rq*Dq+255)/256, 256, 0, stream>>>(We1, We1Th, We1Tl, Dq, Rq);
  splitT<<<(Rq*Dq+255)/256, 256, 0, stream>>>(Wd1, Wd1Th, Wd1Tl, Dq, Rq);
  splitT<<<(Rq*Dq+255)/256, 256, 0, stream>>>(Wa1, Wa1Th, Wa1Tl, Dq, Rq);
  splitT<<<(Dq*Dq+255)/256, 256, 0, stream>>>(Wg,  WgTh,  WgTl,  Dq, Dq);
  splitT<<<(Hq*Rq+255)/256, 256, 0, stream>>>(We2, We2Th, We2Tl, Rq, Hq);
  splitT<<<(Hq*Rq+255)/256, 256, 0, stream>>>(Wd2, Wd2Th, Wd2Tl, Rq, Hq);
  splitT<<<(Hq*Rq+255)/256, 256, 0, stream>>>(Wa2, Wa2Th, Wa2Tl, Rq, Hq);
  splitT<<<(Dq*Hq+255)/256, 256, 0, stream>>>(Wo,  WoTh,  WoTl,  Hq, Dq);

  dim3 blk(256);
  gemm_bf3<128,0><<<dim3(1, BSq/128), blk, 0, stream>>>(x, WkTh, WkTl, k_raw, nullptr, Hq, Dq);
  gemm_bf3<128,0><<<dim3(1, BSq/128), blk, 0, stream>>>(x, WvTh, WvTl, v_raw, nullptr, Hq, Dq);
  gemm_bf3<64,0> <<<dim3(1, BSq/128), blk, 0, stream>>>(x, We1Th, We1Tl, te, nullptr, Rq, Dq);
  gemm_bf3<64,0> <<<dim3(1, BSq/128), blk, 0, stream>>>(x, Wd1Th, Wd1Tl, td, nullptr, Rq, Dq);
  gemm_bf3<64,0> <<<dim3(1, BSq/128), blk, 0, stream>>>(x, Wa1Th, Wa1Tl, ta, nullptr, Rq, Dq);
  gemm_bf3<128,1><<<dim3(1, BSq/128), blk, 0, stream>>>(te, We2Th, We2Tl, etab,   nullptr, Hq, Rq);
  gemm_bf3<128,1><<<dim3(1, BSq/128), blk, 0, stream>>>(td, Wd2Th, Wd2Tl, deltab, nullptr, Hq, Rq);
  gemm_bf3<128,2><<<dim3(1, BSq/128), blk, 0, stream>>>(ta, Wa2Th, Wa2Tl, alphab, nullptr, Hq, Rq);
  conv_ln_kernel<<<dim3(Sq, Bq, 2), dim3(128), 0, stream>>>(
      k_raw, v_raw, conv_w, conv_b, kn_g, kn_b, k_ln, v_c);
  // fused: scan (blocks 0..3, 16 waves) + Wg GEMM (blocks 4..1027)
  fused_scan_wg<<<dim3(4 + (BSq/128)*(Dq/128)), dim3(1024), 0, stream>>>(
      k_ln, v_c, etab, deltab, alphab, mW1, mb1, mW2, mb2, comb,
      x, WgTh, WgTl, glog);
  gemm_bf3<128,3><<<dim3(Dq/128, BSq/128), blk, 0, stream>>>(comb, WoTh, WoTl, out, glog, Dq, Hq);
}